// Round 3
// baseline (736.784 us; speedup 1.0000x reference)
//
#include <hip/hip_runtime.h>
#include <math.h>

#define N_NODES 50000
#define N_EDGES 1600000
#define NFEAT 256
#define NHID 64
#define NCLASS 16

// ---------------- zero-fill: h (3.2M) and out (0.8M) -----------------------
__global__ void zero_kernel(float* __restrict__ h, float* __restrict__ out) {
    int i = blockIdx.x * 256 + threadIdx.x;
    if (i < N_NODES * NHID) h[i] = 0.f;
    if (i < N_NODES * NCLASS) out[i] = 0.f;
}

// ---------------- GEMM1: s1 = x @ W1   [50000,256]x[256,64] ----------------
// block 256 = 4 nodes x 64 cols. x row read is wave-uniform (broadcast);
// W1 read coalesced across lanes; W1 (64KB) stays hot in L1/L2.
__global__ void gemm1_kernel(const float* __restrict__ x,
                             const float* __restrict__ W1,
                             float* __restrict__ s1) {
    int node = blockIdx.x * 4 + (threadIdx.x >> 6);
    int col  = threadIdx.x & 63;
    if (node >= N_NODES) return;
    const float* xr = x + (size_t)node * NFEAT;
    float sum = 0.f;
#pragma unroll 8
    for (int k = 0; k < NFEAT; ++k)
        sum = fmaf(xr[k], W1[k * NHID + col], sum);
    s1[(size_t)node * NHID + col] = sum;
}

// ---------------- SpMM1: h[dst] += w * s1[src]  (64 lanes per edge) --------
// Indices clamped so bad input data can never fault the GPU.
__global__ void spmm1_kernel(const int* __restrict__ src,
                             const int* __restrict__ dst,
                             const float* __restrict__ w,
                             const float* __restrict__ s1,
                             float* __restrict__ h) {
    int e = blockIdx.x * 4 + (threadIdx.x >> 6);
    if (e >= N_EDGES) return;
    int lane = threadIdx.x & 63;
    int s = min(max(src[e], 0), N_NODES - 1);
    int d = min(max(dst[e], 0), N_NODES - 1);
    float wt = w[e];
    float v = wt * s1[(size_t)s * NHID + lane];
    atomicAdd(&h[(size_t)d * NHID + lane], v);
}

// ---------------- bias + ReLU in place on h --------------------------------
__global__ void bias_relu_kernel(float* __restrict__ h,
                                 const float* __restrict__ b1) {
    int i = blockIdx.x * 256 + threadIdx.x;
    if (i >= N_NODES * NHID) return;
    float v = h[i] + b1[i & (NHID - 1)];
    h[i] = v > 0.f ? v : 0.f;
}

// ---------------- GEMM2: s2 = h @ W2   [50000,64]x[64,16] ------------------
// block 256 = 16 nodes x 16 cols. W2 is 4KB, cache-resident.
__global__ void gemm2_kernel(const float* __restrict__ h,
                             const float* __restrict__ W2,
                             float* __restrict__ s2) {
    int node = blockIdx.x * 16 + (threadIdx.x >> 4);
    int col  = threadIdx.x & 15;
    if (node >= N_NODES) return;
    const float* hr = h + (size_t)node * NHID;
    float sum = 0.f;
#pragma unroll 8
    for (int k = 0; k < NHID; ++k)
        sum = fmaf(hr[k], W2[k * NCLASS + col], sum);
    s2[(size_t)node * NCLASS + col] = sum;
}

// ---------------- SpMM2: out[dst] += w * s2[src]  (16 lanes per edge) ------
__global__ void spmm2_kernel(const int* __restrict__ src,
                             const int* __restrict__ dst,
                             const float* __restrict__ w,
                             const float* __restrict__ s2,
                             float* __restrict__ out) {
    int e = blockIdx.x * 16 + (threadIdx.x >> 4);
    if (e >= N_EDGES) return;
    int lane = threadIdx.x & 15;
    int s = min(max(src[e], 0), N_NODES - 1);
    int d = min(max(dst[e], 0), N_NODES - 1);
    float wt = w[e];
    float v = wt * s2[(size_t)s * NCLASS + lane];
    atomicAdd(&out[(size_t)d * NCLASS + lane], v);
}

// ---------------- bias + log_softmax in place on out -----------------------
// one thread per node; 16 classes held in registers.
__global__ void logsoftmax_kernel(float* __restrict__ out,
                                  const float* __restrict__ b2) {
    int n = blockIdx.x * 256 + threadIdx.x;
    if (n >= N_NODES) return;
    float v[NCLASS];
    float mx = -INFINITY;
#pragma unroll
    for (int c = 0; c < NCLASS; ++c) {
        v[c] = out[(size_t)n * NCLASS + c] + b2[c];
        mx = fmaxf(mx, v[c]);
    }
    float ssum = 0.f;
#pragma unroll
    for (int c = 0; c < NCLASS; ++c)
        ssum += expf(v[c] - mx);
    float ls = mx + logf(ssum);
#pragma unroll
    for (int c = 0; c < NCLASS; ++c)
        out[(size_t)n * NCLASS + c] = v[c] - ls;
}

extern "C" void kernel_launch(void* const* d_in, const int* in_sizes, int n_in,
                              void* d_out, int out_size, void* d_ws, size_t ws_size,
                              hipStream_t stream) {
    // ---- defensive shape verification: refuse to launch on any mismatch ----
    // (turns a wrong-assumption crash into a clean absmax failure)
    if (n_in != 8) return;
    const int expected[8] = { N_NODES * NFEAT, NFEAT * NHID, NHID,
                              NHID * NCLASS, NCLASS,
                              N_EDGES, N_EDGES, N_EDGES };
    for (int i = 0; i < 8; ++i)
        if (in_sizes[i] != expected[i]) return;
    if (out_size != N_NODES * NCLASS) return;

    const float* x  = (const float*)d_in[0];
    const float* W1 = (const float*)d_in[1];
    const float* b1 = (const float*)d_in[2];
    const float* W2 = (const float*)d_in[3];
    const float* b2 = (const float*)d_in[4];
    const int* edge_src = (const int*)d_in[5];
    const int* edge_dst = (const int*)d_in[6];
    const float* edge_w = (const float*)d_in[7];
    float* out = (float*)d_out;

    // workspace layout: [s1 / s2 (reused)] [h]  — 25.6 MB total.
    const size_t S1_ELTS = (size_t)N_NODES * NHID;     // 3.2M floats = 12.8 MB
    if (ws_size < 2 * S1_ELTS * sizeof(float)) return; // no OOB, fail cleanly
    float* s1 = (float*)d_ws;
    float* h  = s1 + S1_ELTS;
    float* s2 = s1;                                    // s1 dead after spmm1

    // zero accumulators with a plain kernel (ws/out poisoned 0xAA each call)
    zero_kernel<<<(N_NODES * NHID + 255) / 256, 256, 0, stream>>>(h, out);

    gemm1_kernel<<<(N_NODES + 3) / 4, 256, 0, stream>>>(x, W1, s1);
    spmm1_kernel<<<(N_EDGES + 3) / 4, 256, 0, stream>>>(edge_src, edge_dst, edge_w, s1, h);
    bias_relu_kernel<<<(N_NODES * NHID + 255) / 256, 256, 0, stream>>>(h, b1);
    gemm2_kernel<<<(N_NODES + 15) / 16, 256, 0, stream>>>(h, W2, s2);
    spmm2_kernel<<<(N_EDGES + 15) / 16, 256, 0, stream>>>(edge_src, edge_dst, edge_w, s2, out);
    logsoftmax_kernel<<<(N_NODES + 255) / 256, 256, 0, stream>>>(out, b2);
}

// Round 4
// 613.340 us; speedup vs baseline: 1.2013x; 1.2013x over previous
//
#include <hip/hip_runtime.h>
#include <math.h>

#define N_NODES 50000
#define N_EDGES 1600000
#define NFEAT 256
#define NHID 64
#define NCLASS 16
#define SCAN_B 1024
#define NB ((N_NODES + SCAN_B - 1) / SCAN_B)   // 49 scan blocks

// ======================= CSR build (per call, capture-safe) =================

__global__ void zero_deg_kernel(int* __restrict__ deg) {
    int i = blockIdx.x * 256 + threadIdx.x;
    if (i < N_NODES) deg[i] = 0;
}

__global__ void deg_kernel(const int* __restrict__ dst, int* __restrict__ deg) {
    int e = blockIdx.x * 256 + threadIdx.x;
    if (e >= N_EDGES) return;
    int d = min(max(dst[e], 0), N_NODES - 1);   // clamp: bad data can't fault
    atomicAdd(&deg[d], 1);
}

// block-local exclusive scan of 1024-chunks; block totals to bsum
__global__ void scan1_kernel(const int* __restrict__ deg, int* __restrict__ row_ptr,
                             int* __restrict__ bsum) {
    __shared__ int buf[SCAN_B];
    int t = threadIdx.x;
    int i = blockIdx.x * SCAN_B + t;
    int v = (i < N_NODES) ? deg[i] : 0;
    buf[t] = v;
    __syncthreads();
    for (int off = 1; off < SCAN_B; off <<= 1) {
        int add = (t >= off) ? buf[t - off] : 0;
        __syncthreads();
        buf[t] += add;
        __syncthreads();
    }
    if (i < N_NODES) row_ptr[i] = buf[t] - v;       // exclusive within block
    if (t == SCAN_B - 1) bsum[blockIdx.x] = buf[t]; // block total
}

// exclusive scan of the NB (=49) block totals, single block of 64
__global__ void scan2_kernel(int* __restrict__ bsum) {
    __shared__ int buf[64];
    int t = threadIdx.x;
    int v = (t < NB) ? bsum[t] : 0;
    buf[t] = v;
    __syncthreads();
    for (int off = 1; off < 64; off <<= 1) {
        int add = (t >= off) ? buf[t - off] : 0;
        __syncthreads();
        buf[t] += add;
        __syncthreads();
    }
    if (t < NB) bsum[t] = buf[t] - v;
}

// add block offsets -> final row_ptr; init cursor = row_ptr
__global__ void scan3_kernel(int* __restrict__ row_ptr, const int* __restrict__ bsum,
                             int* __restrict__ cursor) {
    int i = blockIdx.x * SCAN_B + threadIdx.x;
    if (i < N_NODES) {
        int r = row_ptr[i] + bsum[blockIdx.x];
        row_ptr[i] = r;
        cursor[i] = r;
    }
    if (i == 0) row_ptr[N_NODES] = N_EDGES;
}

// scatter edges into dst-sorted order. cursor stays within each row since
// total increments per row == deg[row] (counted with the same clamp).
__global__ void scatter_kernel(const int* __restrict__ src, const int* __restrict__ dst,
                               const float* __restrict__ w, int* __restrict__ cursor,
                               int* __restrict__ csr_src, float* __restrict__ csr_w) {
    int e = blockIdx.x * 256 + threadIdx.x;
    if (e >= N_EDGES) return;
    int d = min(max(dst[e], 0), N_NODES - 1);
    int pos = atomicAdd(&cursor[d], 1);
    csr_src[pos] = min(max(src[e], 0), N_NODES - 1);
    csr_w[pos] = w[e];
}

// ======================= dense GEMMs =======================================

// s1 = x @ W1  [50000,256]x[256,64]; block 256 = 4 nodes x 64 cols
__global__ void gemm1_kernel(const float* __restrict__ x,
                             const float* __restrict__ W1,
                             float* __restrict__ s1) {
    int node = blockIdx.x * 4 + (threadIdx.x >> 6);
    int col  = threadIdx.x & 63;
    if (node >= N_NODES) return;
    const float* xr = x + (size_t)node * NFEAT;
    float sum = 0.f;
#pragma unroll 8
    for (int k = 0; k < NFEAT; ++k)
        sum = fmaf(xr[k], W1[k * NHID + col], sum);
    s1[(size_t)node * NHID + col] = sum;
}

// s2 = h @ W2  [50000,64]x[64,16]; block 256 = 16 nodes x 16 cols
__global__ void gemm2_kernel(const float* __restrict__ h,
                             const float* __restrict__ W2,
                             float* __restrict__ s2) {
    int node = blockIdx.x * 16 + (threadIdx.x >> 4);
    int col  = threadIdx.x & 15;
    if (node >= N_NODES) return;
    const float* hr = h + (size_t)node * NHID;
    float sum = 0.f;
#pragma unroll 8
    for (int k = 0; k < NHID; ++k)
        sum = fmaf(hr[k], W2[k * NCLASS + col], sum);
    s2[(size_t)node * NCLASS + col] = sum;
}

// ======================= CSR SpMM, fused epilogues =========================

// h[n] = relu(sum_j w_j * s1[src_j] + b1); one 64-lane wave per node,
// 2-way unrolled for load ILP. Single non-atomic write, no pre-zero needed.
__global__ void spmm1_csr_kernel(const int* __restrict__ row_ptr,
                                 const int* __restrict__ csr_src,
                                 const float* __restrict__ csr_w,
                                 const float* __restrict__ s1,
                                 const float* __restrict__ b1,
                                 float* __restrict__ h) {
    int node = blockIdx.x * 4 + (threadIdx.x >> 6);
    if (node >= N_NODES) return;
    int lane = threadIdx.x & 63;
    int beg = row_ptr[node], end = row_ptr[node + 1];
    float acc0 = 0.f, acc1 = 0.f;
    int j = beg;
    for (; j + 1 < end; j += 2) {
        int s0 = csr_src[j], s1i = csr_src[j + 1];
        float w0 = csr_w[j], w1 = csr_w[j + 1];
        acc0 = fmaf(w0, s1[(size_t)s0 * NHID + lane], acc0);
        acc1 = fmaf(w1, s1[(size_t)s1i * NHID + lane], acc1);
    }
    if (j < end)
        acc0 = fmaf(csr_w[j], s1[(size_t)csr_src[j] * NHID + lane], acc0);
    float v = acc0 + acc1 + b1[lane];
    h[(size_t)node * NHID + lane] = v > 0.f ? v : 0.f;
}

// out[n] = log_softmax(sum_j w_j * s2[src_j] + b2); 16 lanes per node,
// cross-lane max/sum via shfl_xor within 16-wide groups.
__global__ void spmm2_csr_kernel(const int* __restrict__ row_ptr,
                                 const int* __restrict__ csr_src,
                                 const float* __restrict__ csr_w,
                                 const float* __restrict__ s2,
                                 const float* __restrict__ b2,
                                 float* __restrict__ out) {
    int node = blockIdx.x * 16 + (threadIdx.x >> 4);
    if (node >= N_NODES) return;
    int c = threadIdx.x & 15;
    int beg = row_ptr[node], end = row_ptr[node + 1];
    float acc0 = 0.f, acc1 = 0.f;
    int j = beg;
    for (; j + 1 < end; j += 2) {
        int s0 = csr_src[j], s1i = csr_src[j + 1];
        float w0 = csr_w[j], w1 = csr_w[j + 1];
        acc0 = fmaf(w0, s2[(size_t)s0 * NCLASS + c], acc0);
        acc1 = fmaf(w1, s2[(size_t)s1i * NCLASS + c], acc1);
    }
    if (j < end)
        acc0 = fmaf(csr_w[j], s2[(size_t)csr_src[j] * NCLASS + c], acc0);
    float v = acc0 + acc1 + b2[c];
    float mx = v;
    for (int off = 8; off; off >>= 1) mx = fmaxf(mx, __shfl_xor(mx, off, 16));
    float ss = expf(v - mx);
    for (int off = 8; off; off >>= 1) ss += __shfl_xor(ss, off, 16);
    out[(size_t)node * NCLASS + c] = v - mx - logf(ss);
}

// ======================= fallback path (R3 atomic version) =================

__global__ void zero_kernel(float* __restrict__ h, float* __restrict__ out) {
    int i = blockIdx.x * 256 + threadIdx.x;
    if (i < N_NODES * NHID) h[i] = 0.f;
    if (i < N_NODES * NCLASS) out[i] = 0.f;
}

__global__ void spmm1_kernel(const int* __restrict__ src, const int* __restrict__ dst,
                             const float* __restrict__ w, const float* __restrict__ s1,
                             float* __restrict__ h) {
    int e = blockIdx.x * 4 + (threadIdx.x >> 6);
    if (e >= N_EDGES) return;
    int lane = threadIdx.x & 63;
    int s = min(max(src[e], 0), N_NODES - 1);
    int d = min(max(dst[e], 0), N_NODES - 1);
    float v = w[e] * s1[(size_t)s * NHID + lane];
    atomicAdd(&h[(size_t)d * NHID + lane], v);
}

__global__ void bias_relu_kernel(float* __restrict__ h, const float* __restrict__ b1) {
    int i = blockIdx.x * 256 + threadIdx.x;
    if (i >= N_NODES * NHID) return;
    float v = h[i] + b1[i & (NHID - 1)];
    h[i] = v > 0.f ? v : 0.f;
}

__global__ void spmm2_kernel(const int* __restrict__ src, const int* __restrict__ dst,
                             const float* __restrict__ w, const float* __restrict__ s2,
                             float* __restrict__ out) {
    int e = blockIdx.x * 16 + (threadIdx.x >> 4);
    if (e >= N_EDGES) return;
    int lane = threadIdx.x & 15;
    int s = min(max(src[e], 0), N_NODES - 1);
    int d = min(max(dst[e], 0), N_NODES - 1);
    float v = w[e] * s2[(size_t)s * NCLASS + lane];
    atomicAdd(&out[(size_t)d * NCLASS + lane], v);
}

__global__ void logsoftmax_kernel(float* __restrict__ out, const float* __restrict__ b2) {
    int n = blockIdx.x * 256 + threadIdx.x;
    if (n >= N_NODES) return;
    float v[NCLASS];
    float mx = -INFINITY;
#pragma unroll
    for (int c = 0; c < NCLASS; ++c) {
        v[c] = out[(size_t)n * NCLASS + c] + b2[c];
        mx = fmaxf(mx, v[c]);
    }
    float ssum = 0.f;
#pragma unroll
    for (int c = 0; c < NCLASS; ++c) ssum += expf(v[c] - mx);
    float ls = mx + logf(ssum);
#pragma unroll
    for (int c = 0; c < NCLASS; ++c) out[(size_t)n * NCLASS + c] = v[c] - ls;
}

// ======================= launch ============================================

extern "C" void kernel_launch(void* const* d_in, const int* in_sizes, int n_in,
                              void* d_out, int out_size, void* d_ws, size_t ws_size,
                              hipStream_t stream) {
    if (n_in != 8) return;
    const int expected[8] = { N_NODES * NFEAT, NFEAT * NHID, NHID,
                              NHID * NCLASS, NCLASS, N_EDGES, N_EDGES, N_EDGES };
    for (int i = 0; i < 8; ++i)
        if (in_sizes[i] != expected[i]) return;
    if (out_size != N_NODES * NCLASS) return;

    const float* x  = (const float*)d_in[0];
    const float* W1 = (const float*)d_in[1];
    const float* b1 = (const float*)d_in[2];
    const float* W2 = (const float*)d_in[3];
    const float* b2 = (const float*)d_in[4];
    const int* edge_src = (const int*)d_in[5];
    const int* edge_dst = (const int*)d_in[6];
    const float* edge_w = (const float*)d_in[7];
    float* out = (float*)d_out;

    const size_t S1_ELTS = (size_t)N_NODES * NHID;   // 3.2M
    // CSR-path workspace: s1(3.2M f) h(3.2M f) csr_src(1.6M i) csr_w(1.6M f)
    //                     row_ptr(50001) cursor(50K) deg(50K) bsum(64)
    const size_t CSR_WORDS = 2 * S1_ELTS + 2 * (size_t)N_EDGES
                           + (N_NODES + 1) + N_NODES + N_NODES + 64;
    if (ws_size >= CSR_WORDS * 4) {
        float* s1      = (float*)d_ws;
        float* h       = s1 + S1_ELTS;
        int*   csr_src = (int*)(h + S1_ELTS);
        float* csr_w   = (float*)(csr_src + N_EDGES);
        int*   row_ptr = (int*)(csr_w + N_EDGES);
        int*   cursor  = row_ptr + (N_NODES + 1);
        int*   deg     = cursor + N_NODES;
        int*   bsum    = deg + N_NODES;
        float* s2      = s1;                          // s1 dead after spmm1

        // --- CSR build (reused by both layers) ---
        zero_deg_kernel<<<(N_NODES + 255) / 256, 256, 0, stream>>>(deg);
        deg_kernel<<<(N_EDGES + 255) / 256, 256, 0, stream>>>(edge_dst, deg);
        scan1_kernel<<<NB, SCAN_B, 0, stream>>>(deg, row_ptr, bsum);
        scan2_kernel<<<1, 64, 0, stream>>>(bsum);
        scan3_kernel<<<NB, SCAN_B, 0, stream>>>(row_ptr, bsum, cursor);
        scatter_kernel<<<(N_EDGES + 255) / 256, 256, 0, stream>>>(
            edge_src, edge_dst, edge_w, cursor, csr_src, csr_w);

        // --- layer 1 ---
        gemm1_kernel<<<(N_NODES + 3) / 4, 256, 0, stream>>>(x, W1, s1);
        spmm1_csr_kernel<<<(N_NODES + 3) / 4, 256, 0, stream>>>(
            row_ptr, csr_src, csr_w, s1, b1, h);
        // --- layer 2 ---
        gemm2_kernel<<<(N_NODES + 15) / 16, 256, 0, stream>>>(h, W2, s2);
        spmm2_csr_kernel<<<(N_NODES + 15) / 16, 256, 0, stream>>>(
            row_ptr, csr_src, csr_w, s2, b2, out);
        return;
    }

    // --- fallback: proven atomic path (25.6 MB ws) ---
    if (ws_size < 2 * S1_ELTS * sizeof(float)) return;
    float* s1 = (float*)d_ws;
    float* h  = s1 + S1_ELTS;
    float* s2 = s1;
    zero_kernel<<<(N_NODES * NHID + 255) / 256, 256, 0, stream>>>(h, out);
    gemm1_kernel<<<(N_NODES + 3) / 4, 256, 0, stream>>>(x, W1, s1);
    spmm1_kernel<<<(N_EDGES + 3) / 4, 256, 0, stream>>>(edge_src, edge_dst, edge_w, s1, h);
    bias_relu_kernel<<<(N_NODES * NHID + 255) / 256, 256, 0, stream>>>(h, b1);
    gemm2_kernel<<<(N_NODES + 15) / 16, 256, 0, stream>>>(h, W2, s2);
    spmm2_kernel<<<(N_EDGES + 15) / 16, 256, 0, stream>>>(edge_src, edge_dst, edge_w, s2, out);
    logsoftmax_kernel<<<(N_NODES + 255) / 256, 256, 0, stream>>>(out, b2);
}

// Round 5
// 454.180 us; speedup vs baseline: 1.6222x; 1.3504x over previous
//
#include <hip/hip_runtime.h>
#include <math.h>

#define N_NODES 50000
#define N_EDGES 1600000
#define NFEAT 256
#define NHID 64
#define NCLASS 16
#define SCAN_B 1024
#define NB ((N_NODES + SCAN_B - 1) / SCAN_B)   // 49 scan blocks

// ======================= CSR build (per call, capture-safe) =================

__global__ void zero_deg_kernel(int* __restrict__ deg) {
    int i = blockIdx.x * 256 + threadIdx.x;
    if (i < N_NODES) deg[i] = 0;
}

__global__ void deg_kernel(const int* __restrict__ dst, int* __restrict__ deg) {
    int e = blockIdx.x * 256 + threadIdx.x;
    if (e >= N_EDGES) return;
    int d = min(max(dst[e], 0), N_NODES - 1);   // clamp: bad data can't fault
    atomicAdd(&deg[d], 1);
}

// block-local exclusive scan of 1024-chunks; block totals to bsum
__global__ void scan1_kernel(const int* __restrict__ deg, int* __restrict__ row_ptr,
                             int* __restrict__ bsum) {
    __shared__ int buf[SCAN_B];
    int t = threadIdx.x;
    int i = blockIdx.x * SCAN_B + t;
    int v = (i < N_NODES) ? deg[i] : 0;
    buf[t] = v;
    __syncthreads();
    for (int off = 1; off < SCAN_B; off <<= 1) {
        int add = (t >= off) ? buf[t - off] : 0;
        __syncthreads();
        buf[t] += add;
        __syncthreads();
    }
    if (i < N_NODES) row_ptr[i] = buf[t] - v;       // exclusive within block
    if (t == SCAN_B - 1) bsum[blockIdx.x] = buf[t]; // block total
}

// exclusive scan of the NB (=49) block totals, single block of 64
__global__ void scan2_kernel(int* __restrict__ bsum) {
    __shared__ int buf[64];
    int t = threadIdx.x;
    int v = (t < NB) ? bsum[t] : 0;
    buf[t] = v;
    __syncthreads();
    for (int off = 1; off < 64; off <<= 1) {
        int add = (t >= off) ? buf[t - off] : 0;
        __syncthreads();
        buf[t] += add;
        __syncthreads();
    }
    if (t < NB) bsum[t] = buf[t] - v;
}

// add block offsets -> final row_ptr; init cursor = row_ptr
__global__ void scan3_kernel(int* __restrict__ row_ptr, const int* __restrict__ bsum,
                             int* __restrict__ cursor) {
    int i = blockIdx.x * SCAN_B + threadIdx.x;
    if (i < N_NODES) {
        int r = row_ptr[i] + bsum[blockIdx.x];
        row_ptr[i] = r;
        cursor[i] = r;
    }
    if (i == 0) row_ptr[N_NODES] = N_EDGES;
}

// scatter edges into dst-sorted order
__global__ void scatter_kernel(const int* __restrict__ src, const int* __restrict__ dst,
                               const float* __restrict__ w, int* __restrict__ cursor,
                               int* __restrict__ csr_src, float* __restrict__ csr_w) {
    int e = blockIdx.x * 256 + threadIdx.x;
    if (e >= N_EDGES) return;
    int d = min(max(dst[e], 0), N_NODES - 1);
    int pos = atomicAdd(&cursor[d], 1);
    csr_src[pos] = min(max(src[e], 0), N_NODES - 1);
    csr_w[pos] = w[e];
}

// ======================= dense GEMMs =======================================

// s1 = x @ W1  [50000,256]x[256,64] — LDS + 4x4 register tiling.
// Block: 256 thr = 64 nodes x 64 cols; K chunked by 16.
// Inner loop per k: 2 ds_read_b128 + 16 FMAs (vs 2 VMEM per FMA naive).
#define BK 16
__global__ __launch_bounds__(256) void gemm1_tiled(const float* __restrict__ x,
                                                   const float* __restrict__ W1,
                                                   float* __restrict__ s1) {
    __shared__ float xT[BK][68];   // [k][node], stride 68: 16B-aligned rows, <=2-way write conflicts (free)
    __shared__ float wt[BK][64];   // [k][col]
    int t = threadIdx.x;
    int n_base = blockIdx.x * 64;

    int cq = t & 15;               // col quad -> c0 = 4*cq
    int nq = t >> 4;               // node quad -> n0 = 4*nq (0..15)

    // staging coords: x chunk 64 nodes x 16 k, one float4 per thread
    int ld_node = t >> 2;          // 0..63
    int ld_k4   = (t & 3) * 4;     // 0,4,8,12
    int gnode = min(n_base + ld_node, N_NODES - 1);   // clamp: tail loads stay in-bounds
    const float* xrow = x + (size_t)gnode * NFEAT;
    // W1 chunk 16 k x 64 cols, one float4 per thread
    int wr = t >> 4;               // k in chunk
    int wc = (t & 15) * 4;

    float acc[4][4] = {};

    for (int k0 = 0; k0 < NFEAT; k0 += BK) {
        float4 xv = *(const float4*)(xrow + k0 + ld_k4);
        xT[ld_k4 + 0][ld_node] = xv.x;
        xT[ld_k4 + 1][ld_node] = xv.y;
        xT[ld_k4 + 2][ld_node] = xv.z;
        xT[ld_k4 + 3][ld_node] = xv.w;
        *(float4*)&wt[wr][wc] = *(const float4*)(W1 + (size_t)(k0 + wr) * NHID + wc);
        __syncthreads();
#pragma unroll
        for (int k = 0; k < BK; ++k) {
            float4 a = *(const float4*)&xT[k][4 * nq];
            float4 b = *(const float4*)&wt[k][4 * cq];
            acc[0][0] = fmaf(a.x, b.x, acc[0][0]);
            acc[0][1] = fmaf(a.x, b.y, acc[0][1]);
            acc[0][2] = fmaf(a.x, b.z, acc[0][2]);
            acc[0][3] = fmaf(a.x, b.w, acc[0][3]);
            acc[1][0] = fmaf(a.y, b.x, acc[1][0]);
            acc[1][1] = fmaf(a.y, b.y, acc[1][1]);
            acc[1][2] = fmaf(a.y, b.z, acc[1][2]);
            acc[1][3] = fmaf(a.y, b.w, acc[1][3]);
            acc[2][0] = fmaf(a.z, b.x, acc[2][0]);
            acc[2][1] = fmaf(a.z, b.y, acc[2][1]);
            acc[2][2] = fmaf(a.z, b.z, acc[2][2]);
            acc[2][3] = fmaf(a.z, b.w, acc[2][3]);
            acc[3][0] = fmaf(a.w, b.x, acc[3][0]);
            acc[3][1] = fmaf(a.w, b.y, acc[3][1]);
            acc[3][2] = fmaf(a.w, b.z, acc[3][2]);
            acc[3][3] = fmaf(a.w, b.w, acc[3][3]);
        }
        __syncthreads();
    }

#pragma unroll
    for (int i = 0; i < 4; ++i) {
        int n = n_base + 4 * nq + i;
        if (n < N_NODES)
            *(float4*)&s1[(size_t)n * NHID + 4 * cq] =
                make_float4(acc[i][0], acc[i][1], acc[i][2], acc[i][3]);
    }
}

// s2 = h @ W2  [50000,64]x[64,16]; block 256 = 16 nodes x 16 cols
__global__ void gemm2_kernel(const float* __restrict__ h,
                             const float* __restrict__ W2,
                             float* __restrict__ s2) {
    int node = blockIdx.x * 16 + (threadIdx.x >> 4);
    int col  = threadIdx.x & 15;
    if (node >= N_NODES) return;
    const float* hr = h + (size_t)node * NHID;
    float sum = 0.f;
#pragma unroll 8
    for (int k = 0; k < NHID; ++k)
        sum = fmaf(hr[k], W2[k * NCLASS + col], sum);
    s2[(size_t)node * NCLASS + col] = sum;
}

// ======================= CSR SpMM, fused epilogues =========================

__global__ void spmm1_csr_kernel(const int* __restrict__ row_ptr,
                                 const int* __restrict__ csr_src,
                                 const float* __restrict__ csr_w,
                                 const float* __restrict__ s1,
                                 const float* __restrict__ b1,
                                 float* __restrict__ h) {
    int node = blockIdx.x * 4 + (threadIdx.x >> 6);
    if (node >= N_NODES) return;
    int lane = threadIdx.x & 63;
    int beg = row_ptr[node], end = row_ptr[node + 1];
    float acc0 = 0.f, acc1 = 0.f;
    int j = beg;
    for (; j + 1 < end; j += 2) {
        int s0 = csr_src[j], s1i = csr_src[j + 1];
        float w0 = csr_w[j], w1 = csr_w[j + 1];
        acc0 = fmaf(w0, s1[(size_t)s0 * NHID + lane], acc0);
        acc1 = fmaf(w1, s1[(size_t)s1i * NHID + lane], acc1);
    }
    if (j < end)
        acc0 = fmaf(csr_w[j], s1[(size_t)csr_src[j] * NHID + lane], acc0);
    float v = acc0 + acc1 + b1[lane];
    h[(size_t)node * NHID + lane] = v > 0.f ? v : 0.f;
}

__global__ void spmm2_csr_kernel(const int* __restrict__ row_ptr,
                                 const int* __restrict__ csr_src,
                                 const float* __restrict__ csr_w,
                                 const float* __restrict__ s2,
                                 const float* __restrict__ b2,
                                 float* __restrict__ out) {
    int node = blockIdx.x * 16 + (threadIdx.x >> 4);
    if (node >= N_NODES) return;
    int c = threadIdx.x & 15;
    int beg = row_ptr[node], end = row_ptr[node + 1];
    float acc0 = 0.f, acc1 = 0.f;
    int j = beg;
    for (; j + 1 < end; j += 2) {
        int s0 = csr_src[j], s1i = csr_src[j + 1];
        float w0 = csr_w[j], w1 = csr_w[j + 1];
        acc0 = fmaf(w0, s2[(size_t)s0 * NCLASS + c], acc0);
        acc1 = fmaf(w1, s2[(size_t)s1i * NCLASS + c], acc1);
    }
    if (j < end)
        acc0 = fmaf(csr_w[j], s2[(size_t)csr_src[j] * NCLASS + c], acc0);
    float v = acc0 + acc1 + b2[c];
    float mx = v;
    for (int off = 8; off; off >>= 1) mx = fmaxf(mx, __shfl_xor(mx, off, 16));
    float ss = expf(v - mx);
    for (int off = 8; off; off >>= 1) ss += __shfl_xor(ss, off, 16);
    out[(size_t)node * NCLASS + c] = v - mx - logf(ss);
}

// ======================= fallback path (R3 atomic version) =================

__global__ void zero_kernel(float* __restrict__ h, float* __restrict__ out) {
    int i = blockIdx.x * 256 + threadIdx.x;
    if (i < N_NODES * NHID) h[i] = 0.f;
    if (i < N_NODES * NCLASS) out[i] = 0.f;
}

__global__ void gemm1_kernel(const float* __restrict__ x,
                             const float* __restrict__ W1,
                             float* __restrict__ s1) {
    int node = blockIdx.x * 4 + (threadIdx.x >> 6);
    int col  = threadIdx.x & 63;
    if (node >= N_NODES) return;
    const float* xr = x + (size_t)node * NFEAT;
    float sum = 0.f;
#pragma unroll 8
    for (int k = 0; k < NFEAT; ++k)
        sum = fmaf(xr[k], W1[k * NHID + col], sum);
    s1[(size_t)node * NHID + col] = sum;
}

__global__ void spmm1_kernel(const int* __restrict__ src, const int* __restrict__ dst,
                             const float* __restrict__ w, const float* __restrict__ s1,
                             float* __restrict__ h) {
    int e = blockIdx.x * 4 + (threadIdx.x >> 6);
    if (e >= N_EDGES) return;
    int lane = threadIdx.x & 63;
    int s = min(max(src[e], 0), N_NODES - 1);
    int d = min(max(dst[e], 0), N_NODES - 1);
    float v = w[e] * s1[(size_t)s * NHID + lane];
    atomicAdd(&h[(size_t)d * NHID + lane], v);
}

__global__ void bias_relu_kernel(float* __restrict__ h, const float* __restrict__ b1) {
    int i = blockIdx.x * 256 + threadIdx.x;
    if (i >= N_NODES * NHID) return;
    float v = h[i] + b1[i & (NHID - 1)];
    h[i] = v > 0.f ? v : 0.f;
}

__global__ void spmm2_kernel(const int* __restrict__ src, const int* __restrict__ dst,
                             const float* __restrict__ w, const float* __restrict__ s2,
                             float* __restrict__ out) {
    int e = blockIdx.x * 16 + (threadIdx.x >> 4);
    if (e >= N_EDGES) return;
    int lane = threadIdx.x & 15;
    int s = min(max(src[e], 0), N_NODES - 1);
    int d = min(max(dst[e], 0), N_NODES - 1);
    float v = w[e] * s2[(size_t)s * NCLASS + lane];
    atomicAdd(&out[(size_t)d * NCLASS + lane], v);
}

__global__ void logsoftmax_kernel(float* __restrict__ out, const float* __restrict__ b2) {
    int n = blockIdx.x * 256 + threadIdx.x;
    if (n >= N_NODES) return;
    float v[NCLASS];
    float mx = -INFINITY;
#pragma unroll
    for (int c = 0; c < NCLASS; ++c) {
        v[c] = out[(size_t)n * NCLASS + c] + b2[c];
        mx = fmaxf(mx, v[c]);
    }
    float ssum = 0.f;
#pragma unroll
    for (int c = 0; c < NCLASS; ++c) ssum += expf(v[c] - mx);
    float ls = mx + logf(ssum);
#pragma unroll
    for (int c = 0; c < NCLASS; ++c) out[(size_t)n * NCLASS + c] = v[c] - ls;
}

// ======================= launch ============================================

extern "C" void kernel_launch(void* const* d_in, const int* in_sizes, int n_in,
                              void* d_out, int out_size, void* d_ws, size_t ws_size,
                              hipStream_t stream) {
    if (n_in != 8) return;
    const int expected[8] = { N_NODES * NFEAT, NFEAT * NHID, NHID,
                              NHID * NCLASS, NCLASS, N_EDGES, N_EDGES, N_EDGES };
    for (int i = 0; i < 8; ++i)
        if (in_sizes[i] != expected[i]) return;
    if (out_size != N_NODES * NCLASS) return;

    const float* x  = (const float*)d_in[0];
    const float* W1 = (const float*)d_in[1];
    const float* b1 = (const float*)d_in[2];
    const float* W2 = (const float*)d_in[3];
    const float* b2 = (const float*)d_in[4];
    const int* edge_src = (const int*)d_in[5];
    const int* edge_dst = (const int*)d_in[6];
    const float* edge_w = (const float*)d_in[7];
    float* out = (float*)d_out;

    const size_t S1_ELTS = (size_t)N_NODES * NHID;   // 3.2M
    const size_t CSR_WORDS = 2 * S1_ELTS + 2 * (size_t)N_EDGES
                           + (N_NODES + 1) + N_NODES + N_NODES + 64;
    if (ws_size >= CSR_WORDS * 4) {
        float* s1      = (float*)d_ws;
        float* h       = s1 + S1_ELTS;
        int*   csr_src = (int*)(h + S1_ELTS);
        float* csr_w   = (float*)(csr_src + N_EDGES);
        int*   row_ptr = (int*)(csr_w + N_EDGES);
        int*   cursor  = row_ptr + (N_NODES + 1);
        int*   deg     = cursor + N_NODES;
        int*   bsum    = deg + N_NODES;
        float* s2      = s1;                          // s1 dead after spmm1

        // --- CSR build (reused by both layers) ---
        zero_deg_kernel<<<(N_NODES + 255) / 256, 256, 0, stream>>>(deg);
        deg_kernel<<<(N_EDGES + 255) / 256, 256, 0, stream>>>(edge_dst, deg);
        scan1_kernel<<<NB, SCAN_B, 0, stream>>>(deg, row_ptr, bsum);
        scan2_kernel<<<1, 64, 0, stream>>>(bsum);
        scan3_kernel<<<NB, SCAN_B, 0, stream>>>(row_ptr, bsum, cursor);
        scatter_kernel<<<(N_EDGES + 255) / 256, 256, 0, stream>>>(
            edge_src, edge_dst, edge_w, cursor, csr_src, csr_w);

        // --- layer 1 ---
        gemm1_tiled<<<(N_NODES + 63) / 64, 256, 0, stream>>>(x, W1, s1);
        spmm1_csr_kernel<<<(N_NODES + 3) / 4, 256, 0, stream>>>(
            row_ptr, csr_src, csr_w, s1, b1, h);
        // --- layer 2 ---
        gemm2_kernel<<<(N_NODES + 15) / 16, 256, 0, stream>>>(h, W2, s2);
        spmm2_csr_kernel<<<(N_NODES + 15) / 16, 256, 0, stream>>>(
            row_ptr, csr_src, csr_w, s2, b2, out);
        return;
    }

    // --- fallback: proven atomic path (25.6 MB ws) ---
    if (ws_size < 2 * S1_ELTS * sizeof(float)) return;
    float* s1 = (float*)d_ws;
    float* h  = s1 + S1_ELTS;
    float* s2 = s1;
    zero_kernel<<<(N_NODES * NHID + 255) / 256, 256, 0, stream>>>(h, out);
    gemm1_kernel<<<(N_NODES + 3) / 4, 256, 0, stream>>>(x, W1, s1);
    spmm1_kernel<<<(N_EDGES + 3) / 4, 256, 0, stream>>>(edge_src, edge_dst, edge_w, s1, h);
    bias_relu_kernel<<<(N_NODES * NHID + 255) / 256, 256, 0, stream>>>(h, b1);
    gemm2_kernel<<<(N_NODES + 15) / 16, 256, 0, stream>>>(h, W2, s2);
    spmm2_kernel<<<(N_EDGES + 15) / 16, 256, 0, stream>>>(edge_src, edge_dst, edge_w, s2, out);
    logsoftmax_kernel<<<(N_NODES + 255) / 256, 256, 0, stream>>>(out, b2);
}